// Round 2
// baseline (418.853 us; speedup 1.0000x reference)
//
#include <hip/hip_runtime.h>
#include <math.h>

#define B_DIM 16
#define C_DIM 256
#define L_DIM 8192
#define D_INNER 512
#define ATT 64
#define TL 128   // l values per block

// ws layout (floats):
//   [0]              qk_scale = <wq,wk>/sqrt(64)
//   [64 .. 64+512)   wo_v[d] = sum_a w_out[d][a]*wv[a]

__global__ __launch_bounds__(512) void prep_kernel(
    const float* __restrict__ wq, const float* __restrict__ wk,
    const float* __restrict__ wv, const float* __restrict__ w_out,
    float* __restrict__ ws) {
    int d = threadIdx.x;  // 0..511
    float acc = 0.f;
    #pragma unroll
    for (int a = 0; a < ATT; ++a) acc += w_out[d * ATT + a] * wv[a];
    ws[64 + d] = acc;
    if (d == 0) {
        float qk = 0.f;
        #pragma unroll
        for (int a = 0; a < ATT; ++a) qk += wq[a] * wk[a];
        ws[0] = qk * 0.125f;  // 1/sqrt(64)
    }
}

// Block = (b, l-tile of 128). Threads = 4 c-groups x 64 l-lanes (float2/lane).
// Pass1: sum/min/max over c (split 4-way, LDS combine). Pass2: exp-weighted
// pool (LDS combine). Epilogue: out[b, 0:512, l_tile] = pooled * wo_v.
__global__ __launch_bounds__(256) void fused_kernel(
    const float* __restrict__ h_v, const float* __restrict__ ws,
    float* __restrict__ out) {
    __shared__ float2 red_a[4][64];
    __shared__ float2 red_b[4][64];
    __shared__ float2 red_c[4][64];
    __shared__ float  pool_l[TL];
    __shared__ float  s_wov[D_INNER];

    const int t    = threadIdx.x;
    const int cg   = t >> 6;        // 0..3  (c-group)
    const int lane = t & 63;        // l-lane within tile
    const int b    = blockIdx.x >> 6;   // 64 l-tiles per b
    const int lt   = blockIdx.x & 63;
    const int l0   = lt * TL;

    // Stage wo_v into LDS (prep_kernel already ran, stream-ordered).
    s_wov[t]       = ws[64 + t];
    s_wov[t + 256] = ws[64 + t + 256];
    const float t_scale = ws[0];

    const float* src = h_v + (size_t)b * (C_DIM * L_DIM) + l0 + lane * 2;
    const int c0 = cg * 64;

    // ---- Pass 1: partial sum / min / max over 64 c values ----
    float2 s  = make_float2(0.f, 0.f);
    float2 mn = make_float2(INFINITY, INFINITY);
    float2 mx = make_float2(-INFINITY, -INFINITY);
    #pragma unroll 8
    for (int c = 0; c < 64; ++c) {
        float2 v = *(const float2*)(src + (size_t)(c0 + c) * L_DIM);
        s.x += v.x; s.y += v.y;
        mn.x = fminf(mn.x, v.x); mx.x = fmaxf(mx.x, v.x);
        mn.y = fminf(mn.y, v.y); mx.y = fmaxf(mx.y, v.y);
    }
    red_a[cg][lane] = s;
    red_b[cg][lane] = mn;
    red_c[cg][lane] = mx;
    __syncthreads();

    // Combine across the 4 c-groups (redundant per-cg, broadcast LDS reads).
    float2 ts  = red_a[0][lane];
    float2 tmn = red_b[0][lane];
    float2 tmx = red_c[0][lane];
    #pragma unroll
    for (int g = 1; g < 4; ++g) {
        float2 a = red_a[g][lane], n = red_b[g][lane], x = red_c[g][lane];
        ts.x += a.x; ts.y += a.y;
        tmn.x = fminf(tmn.x, n.x); tmn.y = fminf(tmn.y, n.y);
        tmx.x = fmaxf(tmx.x, x.x); tmx.y = fmaxf(tmx.y, x.y);
    }
    __syncthreads();  // reads done before LDS reuse below

    const float t0 = ts.x * (1.0f / C_DIM) * t_scale;
    const float t1 = ts.y * (1.0f / C_DIM) * t_scale;
    // logits = h*t; max_c = max(t*min_c h, t*max_c h)
    const float m0 = fmaxf(tmn.x * t0, tmx.x * t0);
    const float m1 = fmaxf(tmn.y * t1, tmx.y * t1);

    // ---- Pass 2: partial exp-sum and exp-weighted sum (L3-resident reread) ----
    float2 se = make_float2(0.f, 0.f);
    float2 sp = make_float2(0.f, 0.f);
    #pragma unroll 8
    for (int c = 0; c < 64; ++c) {
        float2 v = *(const float2*)(src + (size_t)(c0 + c) * L_DIM);
        float e0 = __expf(v.x * t0 - m0);
        float e1 = __expf(v.y * t1 - m1);
        se.x += e0; se.y += e1;
        sp.x += e0 * v.x; sp.y += e1 * v.y;
    }
    red_a[cg][lane] = se;
    red_b[cg][lane] = sp;
    __syncthreads();

    float2 tse = red_a[0][lane];
    float2 tsp = red_b[0][lane];
    #pragma unroll
    for (int g = 1; g < 4; ++g) {
        float2 a = red_a[g][lane], p = red_b[g][lane];
        tse.x += a.x; tse.y += a.y;
        tsp.x += p.x; tsp.y += p.y;
    }
    if (cg == 0) {
        ((float2*)pool_l)[lane] = make_float2(tsp.x / tse.x, tsp.y / tse.y);
    }
    __syncthreads();

    // ---- Epilogue: out[b, d, l0:l0+128] = pool * wo_v[d] ----
    const int dg = t >> 5;   // 0..7
    const int lq = t & 31;   // float4 index within 128 l
    float4 pv = ((const float4*)pool_l)[lq];
    float* ob = out + (size_t)b * ((size_t)D_INNER * L_DIM) + l0 + lq * 4;
    #pragma unroll 8
    for (int d = dg; d < D_INNER; d += 8) {
        float w = s_wov[d];
        float4 o;
        o.x = pv.x * w; o.y = pv.y * w; o.z = pv.z * w; o.w = pv.w * w;
        *(float4*)(ob + (size_t)d * L_DIM) = o;
    }
}

extern "C" void kernel_launch(void* const* d_in, const int* in_sizes, int n_in,
                              void* d_out, int out_size, void* d_ws, size_t ws_size,
                              hipStream_t stream) {
    const float* h_v   = (const float*)d_in[0];
    const float* wq    = (const float*)d_in[1];
    const float* wk    = (const float*)d_in[2];
    const float* wv    = (const float*)d_in[3];
    const float* w_out = (const float*)d_in[4];
    float* ws  = (float*)d_ws;
    float* out = (float*)d_out;

    hipLaunchKernelGGL(prep_kernel, dim3(1), dim3(512), 0, stream,
                       wq, wk, wv, w_out, ws);
    // B * (L/TL) = 16 * 64 = 1024 blocks
    hipLaunchKernelGGL(fused_kernel, dim3(1024), dim3(256), 0, stream,
                       h_v, ws, out);
}

// Round 3
// 367.888 us; speedup vs baseline: 1.1385x; 1.1385x over previous
//
#include <hip/hip_runtime.h>
#include <math.h>

#define B_DIM 16
#define C_DIM 256
#define L_DIM 8192
#define D_INNER 512
#define ATT 64
#define NK 11   // power sums S_1..S_11 (Taylor order K=10)

// ws layout (floats):
//   [0]                qk_scale = <wq,wk>/sqrt(64)
//   [64 .. 64+512)     wo_v[d] = sum_a w_out[d][a]*wv[a]
//   [1024 .. 1024+B*L) pooled[b][l]

__global__ __launch_bounds__(512) void prep_kernel(
    const float* __restrict__ wq, const float* __restrict__ wk,
    const float* __restrict__ wv, const float* __restrict__ w_out,
    float* __restrict__ ws) {
    int d = threadIdx.x;  // 0..511
    float acc = 0.f;
    #pragma unroll
    for (int a = 0; a < ATT; ++a) acc += w_out[d * ATT + a] * wv[a];
    ws[64 + d] = acc;
    if (d == 0) {
        float qk = 0.f;
        #pragma unroll
        for (int a = 0; a < ATT; ++a) qk += wq[a] * wk[a];
        ws[0] = qk * 0.125f;  // 1/sqrt(64)
    }
}

// Single pass over h_v. Block = (b, 128-l tile); threads = 4 c-groups x 64
// l-lanes (float2/lane). Each thread accumulates power sums S_1..S_11 of its
// 64 c values; LDS-combine across c-groups; evaluate Taylor series of
// softmax-pool in closed form; write pooled[b,l].
//   den = sum_c exp(t*h) = sum_k t^k/k! S_k   (S_0 = 256)
//   num = sum_c h*exp(t*h) = sum_k t^k/k! S_{k+1}
__global__ __launch_bounds__(256) void pooled_kernel(
    const float* __restrict__ h_v, const float* __restrict__ ws,
    float* __restrict__ pooled) {
    __shared__ float2 red[4][64][NK];  // 22.5 KB

    const int t    = threadIdx.x;
    const int cg   = t >> 6;          // 0..3
    const int lane = t & 63;          // l-lane (float2) within 128-l tile
    const int b    = blockIdx.x >> 6; // 64 tiles per b
    const int lt   = blockIdx.x & 63;

    const float* src = h_v + (size_t)b * (C_DIM * L_DIM) + lt * 128 + lane * 2
                           + (size_t)cg * 64 * L_DIM;

    float2 S[NK];
    #pragma unroll
    for (int j = 0; j < NK; ++j) S[j] = make_float2(0.f, 0.f);

    #pragma unroll 4
    for (int c = 0; c < 64; ++c) {
        float2 v = *(const float2*)(src + (size_t)c * L_DIM);
        float px = v.x, py = v.y;
        S[0].x += px; S[0].y += py;
        #pragma unroll
        for (int j = 1; j < NK; ++j) {
            px *= v.x; py *= v.y;
            S[j].x += px; S[j].y += py;
        }
    }
    #pragma unroll
    for (int j = 0; j < NK; ++j) red[cg][lane][j] = S[j];
    __syncthreads();

    if (cg == 0) {
        #pragma unroll
        for (int g = 1; g < 4; ++g) {
            #pragma unroll
            for (int j = 0; j < NK; ++j) {
                float2 a = red[g][lane][j];
                S[j].x += a.x; S[j].y += a.y;
            }
        }
        const float qs = ws[0];
        const float t0 = S[0].x * (1.0f / C_DIM) * qs;
        const float t1 = S[0].y * (1.0f / C_DIM) * qs;

        const float invfact[NK] = {
            1.f, 1.f, 0.5f, 1.f/6.f, 1.f/24.f, 1.f/120.f, 1.f/720.f,
            1.f/5040.f, 1.f/40320.f, 1.f/362880.f, 1.f/3628800.f};

        float den0 = (float)C_DIM, num0 = S[0].x;
        float den1 = (float)C_DIM, num1 = S[0].y;
        float tp0 = 1.f, tp1 = 1.f;
        #pragma unroll
        for (int k = 1; k <= 10; ++k) {
            tp0 *= t0; tp1 *= t1;
            float c0 = tp0 * invfact[k];
            float c1 = tp1 * invfact[k];
            den0 += c0 * S[k - 1].x;  num0 += c0 * S[k].x;
            den1 += c1 * S[k - 1].y;  num1 += c1 * S[k].y;
        }
        float2 o;
        o.x = num0 / den0;
        o.y = num1 / den1;
        ((float2*)(pooled + (size_t)b * L_DIM + lt * 128))[lane] = o;
    }
}

// out[b,d,l] = pooled[b,l] * wo_v[d]; one float4 per thread, pure stream write.
__global__ __launch_bounds__(256) void write_kernel(
    const float* __restrict__ ws, float* __restrict__ out) {
    const float* wo_v   = ws + 64;
    const float* pooled = ws + 1024;
    int i   = blockIdx.x * 256 + threadIdx.x;  // float4 index
    int l4  = i & 2047;                        // L/4 = 2048
    int tmp = i >> 11;
    int d   = tmp & 511;
    int b   = tmp >> 9;
    float4 p = ((const float4*)(pooled + (size_t)b * L_DIM))[l4];
    float  w = wo_v[d];
    float4 o;
    o.x = p.x * w; o.y = p.y * w; o.z = p.z * w; o.w = p.w * w;
    ((float4*)out)[i] = o;
}

extern "C" void kernel_launch(void* const* d_in, const int* in_sizes, int n_in,
                              void* d_out, int out_size, void* d_ws, size_t ws_size,
                              hipStream_t stream) {
    const float* h_v   = (const float*)d_in[0];
    const float* wq    = (const float*)d_in[1];
    const float* wk    = (const float*)d_in[2];
    const float* wv    = (const float*)d_in[3];
    const float* w_out = (const float*)d_in[4];
    float* ws  = (float*)d_ws;
    float* out = (float*)d_out;

    hipLaunchKernelGGL(prep_kernel, dim3(1), dim3(512), 0, stream,
                       wq, wk, wv, w_out, ws);
    // B * (L/128) = 1024 blocks
    hipLaunchKernelGGL(pooled_kernel, dim3(1024), dim3(256), 0, stream,
                       h_v, ws, ws + 1024);
    // B*D*L/4 = 16777216 float4 stores
    hipLaunchKernelGGL(write_kernel, dim3(65536), dim3(256), 0, stream,
                       ws, out);
}